// Round 6
// baseline (135.949 us; speedup 1.0000x reference)
//
#include <hip/hip_runtime.h>
#include <math.h>

// Problem constants (from setup_inputs): x is (32, 9, 256, 256) fp32.
#define BATCH 32
#define CHANS 9
#define HH 256
#define WW 256

typedef float f32x4 __attribute__((ext_vector_type(4)));

// One wave (64 lanes x float4 = 256 px) computes FOUR adjacent output rows.
// No LDS, no shuffles: each lane loads its 4-px chunk of 6 source rows plus
// 1-px left/right halos directly (coalesced adjacent dwords, cache-hit).
// 18 independent loads in flight -> one wait -> straight-line VALU -> 4 stores.
__global__ __launch_bounds__(256) void edge_router_kernel(
    const float* __restrict__ x,
    const float* __restrict__ alpha_p,
    const float* __restrict__ scale_p,
    const int*   __restrict__ year,
    float* __restrict__ out)
{
    const int tid   = threadIdx.x;
    const int lane  = tid & 63;
    const int gwave = blockIdx.x * 4 + (tid >> 6);
    const int grp   = gwave & 63;           // 64 groups of 4 rows per plane
    const int plane = gwave >> 6;           // b*CHANS + c
    const int b     = plane / CHANS;
    const int r0    = grp * 4;
    const int xq    = lane * 4;

    const float* __restrict__ p = x   + (size_t)plane * (HH * WW);
    float*       __restrict__ q = out + (size_t)plane * (HH * WW);

    // ---- 6 source rows (r0-1 .. r0+4), each: main f32x4 + left/right halo ----
    const int xl = (xq == 0)      ? 0      : xq - 1;   // clamped halo addrs
    const int xr = (xq == WW - 4) ? WW - 1 : xq + 4;
    float L[6], R[6];
    f32x4 M[6];
    #pragma unroll
    for (int i = 0; i < 6; ++i) {
        int y  = r0 - 1 + i;
        int yc = min(max(y, 0), HH - 1);
        const float* rowp = p + (size_t)yc * WW;
        M[i] = *reinterpret_cast<const f32x4*>(rowp + xq);
        L[i] = rowp[xl];
        R[i] = rowp[xr];
    }
    // horizontal zero padding (per-lane, only edge lanes)
    if (lane == 0)  { L[0]=L[1]=L[2]=L[3]=L[4]=L[5]=0.f; }
    if (lane == 63) { R[0]=R[1]=R[2]=R[3]=R[4]=R[5]=0.f; }
    // vertical zero padding (wave-uniform, only top/bottom groups)
    if (r0 == 0)      { M[0] = (f32x4)0.f; L[0] = 0.f; R[0] = 0.f; }
    if (r0 + 4 == HH) { M[5] = (f32x4)0.f; L[5] = 0.f; R[5] = 0.f; }

    // ---- per-sample operator parameters (uniform across wave) ----
    const int yr = year[b];
    float w0, w1, eps, post;
    if (yr == 2019) {            // sobel
        w0 = 1.f; w1 = 2.f; eps = 1e-8f; post = 1.f;
    } else if (yr == 2020) {     // scharr
        w0 = 3.f; w1 = 10.f; eps = 1e-8f; post = 1.f;
    } else {                     // learnable (2018, 2021)
        const float a = 1.f / (1.f + expf(-alpha_p[0]));
        const float m = 10.f - 8.f * a;          // max|kernel| element
        w0 = (3.f - 2.f * a) / m;
        w1 = 1.f;
        eps = 1e-6f;
        post = 1.f / (1.f + expf(-scale_p[0]));
    }

    // ---- 4 output rows, vertical-first separable conv, no cross-lane ----
    #pragma unroll
    for (int j = 0; j < 4; ++j) {
        // window rows: j (above), j+1 (center), j+2 (below)
        // t = vertical smooth, u = vertical diff, at columns -1..4
        float tm = fmaf(w1, L[j+1], w0 * (L[j] + L[j+2]));
        float um = L[j+2] - L[j];
        float tp = fmaf(w1, R[j+1], w0 * (R[j] + R[j+2]));
        float up = R[j+2] - R[j];
        f32x4 t, u;
        t.x = fmaf(w1, M[j+1].x, w0 * (M[j].x + M[j+2].x));
        t.y = fmaf(w1, M[j+1].y, w0 * (M[j].y + M[j+2].y));
        t.z = fmaf(w1, M[j+1].z, w0 * (M[j].z + M[j+2].z));
        t.w = fmaf(w1, M[j+1].w, w0 * (M[j].w + M[j+2].w));
        u = M[j+2] - M[j];

        f32x4 gx, gy, o;
        gx.x = t.y - tm;   gx.y = t.z - t.x;
        gx.z = t.w - t.y;  gx.w = tp - t.z;
        gy.x = fmaf(w1, u.x, w0 * (um  + u.y));
        gy.y = fmaf(w1, u.y, w0 * (u.x + u.z));
        gy.z = fmaf(w1, u.z, w0 * (u.y + u.w));
        gy.w = fmaf(w1, u.w, w0 * (u.z + up));

        o.x = sqrtf(fmaf(gx.x, gx.x, fmaf(gy.x, gy.x, eps))) * post;
        o.y = sqrtf(fmaf(gx.y, gx.y, fmaf(gy.y, gy.y, eps))) * post;
        o.z = sqrtf(fmaf(gx.z, gx.z, fmaf(gy.z, gy.z, eps))) * post;
        o.w = sqrtf(fmaf(gx.w, gx.w, fmaf(gy.w, gy.w, eps))) * post;

        *reinterpret_cast<f32x4*>(q + (size_t)(r0 + j) * WW + xq) = o;
    }
}

extern "C" void kernel_launch(void* const* d_in, const int* in_sizes, int n_in,
                              void* d_out, int out_size, void* d_ws, size_t ws_size,
                              hipStream_t stream) {
    const float* x     = (const float*)d_in[0];
    const float* alpha = (const float*)d_in[1];
    const float* scale = (const float*)d_in[2];
    const int*   year  = (const int*)  d_in[3];
    float* out = (float*)d_out;

    const int waves  = BATCH * CHANS * (HH / 4);   // 18432 waves, 4 rows each
    const int blocks = waves / 4;                  // 4 waves/block = 4608
    edge_router_kernel<<<blocks, 256, 0, stream>>>(x, alpha, scale, year, out);
}